// Round 4
// baseline (192.147 us; speedup 1.0000x reference)
//
#include <hip/hip_runtime.h>
#include <hip/hip_fp16.h>

// MLPLowRankPredictor: FastFood (B,H,P,G,H,S) low-rank weight perturbation + 3-layer MLP.
// SEQ=64 BATCH=32 -> N=2048 tokens. Z=128, X=32, H=128, Y=16.
// Blocks: wd0: 0..31 (4 rows x 32 cols), bd0: 32, wd1: 33..160, bd1: 161,
//         wd2: 162..177, bd2: 178 (first 16 elems).
//
// R4 theory: per-wave stall latency (~25 cyc/inst) from (a) SGPR-starved serial
// s_load chains for the 2.5KB block-uniform params (SGPR=112 < 640 dwords needed),
// each reload forcing lgkmcnt(0) drains that also serialize the DS pipe; (b) 5
// unnecessary __syncthreads per block (per-lane-private LDS columns + in-order DS
// make them dead weight); (c) fully uncoalesced token-major global accesses
// (per-lane 512B stride = 64 scattered segments/instr). Fixes:
//  - params staged to LDS once per block, read as broadcast ds_read (vmcnt-free,
//    in-order, counted waits) -> no SMEM in hot path.
//  - 4-wave (256-thr) blocks, per-wave-private 16KB perm slices, ONE barrier total.
//  - all token-major arrays transposed to pair-interleaved [c2][t] layout
//    (tiny pre-kernel for z/x; intermediates written transposed) -> all hot
//    loads/stores coalesced.

#define ZD 128
#define XD 32
#define HD 128
#define YD 16
#define NTOK 2048

__device__ __forceinline__ float2 pk_add(float2 a, float2 b) {
  float2 d;
  asm("v_pk_add_f32 %0, %1, %2" : "=v"(d) : "v"(a), "v"(b));
  return d;
}
__device__ __forceinline__ float2 pk_sub(float2 a, float2 b) {
  float2 d;
  asm("v_pk_add_f32 %0, %1, %2 neg_lo:[0,1] neg_hi:[0,1]" : "=v"(d) : "v"(a), "v"(b));
  return d;
}

// In-register FWHT over 128 elems stored as w[m] = (v[2m], v[2m+1]).
__device__ __forceinline__ void fwht128p(float2 w[64]) {
#pragma unroll
  for (int m = 0; m < 64; m++) {
    float a = w[m].x, b = w[m].y;
    w[m].x = a + b; w[m].y = a - b;
  }
#pragma unroll
  for (int sig = 1; sig < 64; sig <<= 1) {
#pragma unroll
    for (int m = 0; m < 64; m++) {
      if ((m & sig) == 0) {
        float2 a = w[m], b = w[m + sig];
        w[m] = pk_add(a, b);
        w[m + sig] = pk_sub(a, b);
      }
    }
  }
}

// zT2 layout: zT2[m*NTOK + t] = (z[t][2m], z[t][2m+1]) -- coalesced across lanes.
__device__ __forceinline__ void load128T(float2 w[64], const float2* __restrict__ zT2, int t) {
#pragma unroll
  for (int m = 0; m < 64; m++) w[m] = zT2[(size_t)m * NTOK + t];
}

// Per-wave FastFood block using LDS-staged params. perm = wave-private 4096-dword
// slice (16KB). Each lane touches only dwords [*, lane] -> no barriers needed
// (in-order DS per wave). Bank: addr%32 == lane%32 -> 2 lanes/bank (free);
// param reads are same-address broadcasts (free).
__device__ __forceinline__ void ff_block(float2 w[64], unsigned int* perm, int lane,
    const float* pB, const float* pG, const float* pS, const int* pP) {
  const float2* B2 = (const float2*)pB;
  const float2* G2 = (const float2*)pG;
  const float2* S2 = (const float2*)pS;
  const int2*   P2 = (const int2*)pP;
#pragma unroll
  for (int m = 0; m < 64; m++) { float2 b = B2[m]; w[m].x *= b.x; w[m].y *= b.y; }
  fwht128p(w);
#pragma unroll
  for (int m = 0; m < 64; m++) {
    __half2 h2v = __floats2half2_rn(w[m].x, w[m].y);
    perm[m * 64 + lane] = *(const unsigned int*)&h2v;
  }
  const __half* ph = (const __half*)perm;
#pragma unroll
  for (int m = 0; m < 64; m++) {
    int2 pp = P2[m];
    float2 g = G2[m];
    w[m].x = g.x * __half2float(ph[(pp.x >> 1) * 128 + 2 * lane + (pp.x & 1)]);
    w[m].y = g.y * __half2float(ph[(pp.y >> 1) * 128 + 2 * lane + (pp.y & 1)]);
  }
  fwht128p(w);
#pragma unroll
  for (int m = 0; m < 64; m++) { float2 s = S2[m]; w[m].x *= s.x; w[m].y *= s.y; }
}

// Stage B/G/S/P (+ one 128-float W row) into LDS; one wave per array. The ONLY
// __syncthreads() in any kernel.
__device__ __forceinline__ void stage_params(int tid,
    const float* __restrict__ ffB, const float* __restrict__ ffG,
    const float* __restrict__ ffS, const int* __restrict__ ffP, int j,
    const float* __restrict__ Wrow,
    float* pB, float* pG, float* pS, int* pP, float* pW) {
  const int wsub = tid >> 6, ln = tid & 63;
  if (wsub == 0) {
    ((float2*)pB)[ln] = ((const float2*)(ffB + (size_t)j * ZD))[ln];
    ((float2*)pW)[ln] = ((const float2*)Wrow)[ln];
  } else if (wsub == 1) {
    ((float2*)pG)[ln] = ((const float2*)(ffG + (size_t)j * ZD))[ln];
  } else if (wsub == 2) {
    ((float2*)pS)[ln] = ((const float2*)(ffS + (size_t)j * ZD))[ln];
  } else {
    ((int2*)pP)[ln] = ((const int2*)(ffP + (size_t)j * ZD))[ln];
  }
  __syncthreads();
}

// K0: transpose z and x into pair-interleaved [c2][t] layout. Reads scattered
// (once), writes coalesced. grid(32), 64 threads.
__global__ __launch_bounds__(64) void k0_transpose(
    const float* __restrict__ z, const float* __restrict__ x,
    float2* __restrict__ zT2, float2* __restrict__ xT2) {
  const int t = blockIdx.x * 64 + threadIdx.x;
  const float4* z4 = (const float4*)(z + (size_t)t * ZD);
#pragma unroll
  for (int k = 0; k < 32; k++) {
    float4 f = z4[k];
    zT2[(size_t)(2 * k) * NTOK + t] = make_float2(f.x, f.y);
    zT2[(size_t)(2 * k + 1) * NTOK + t] = make_float2(f.z, f.w);
  }
  const float4* x4 = (const float4*)(x + (size_t)t * XD);
#pragma unroll
  for (int k = 0; k < 8; k++) {
    float4 f = x4[k];
    xT2[(size_t)(2 * k) * NTOK + t] = make_float2(f.x, f.y);
    xT2[(size_t)(2 * k + 1) * NTOK + t] = make_float2(f.z, f.w);
  }
}

// K1: grid (8, 35), 256 thr. b<32: weight rows 4b..4b+3 -> h1T2 (pre-relu, pre-bd0).
//     b=32: bd0 -> bd0T2.  b=33: bd1 -> h2bT2.  b=34: bd2 -> bd2v.
__global__ __launch_bounds__(256) void k1_layer0(
    const float2* __restrict__ xT2, const float2* __restrict__ zT2,
    const float* __restrict__ W0, const float* __restrict__ b0,
    const float* __restrict__ ffB, const float* __restrict__ ffG,
    const float* __restrict__ ffS, const int* __restrict__ ffP,
    float2* __restrict__ h1T2, float2* __restrict__ bd0T2,
    float2* __restrict__ h2bT2, float* __restrict__ bd2v) {
  __shared__ unsigned int ldsPerm[4 * 4096];
  __shared__ float pB[128], pG[128], pS[128], pW[128];
  __shared__ int pP[128];
  const int tid = threadIdx.x, lane = tid & 63, wsub = tid >> 6;
  const int b = blockIdx.y;
  const int j = (b < 32) ? b : (b == 32 ? 32 : (b == 33 ? 161 : 178));
  const int t = (blockIdx.x * 4 + wsub) * 64 + lane;

  stage_params(tid, ffB, ffG, ffS, ffP, j, W0 + (size_t)(b < 32 ? b : 0) * 128,
               pB, pG, pS, pP, pW);

  float2 w[64];
  load128T(w, zT2, t);
  ff_block(w, ldsPerm + wsub * 4096, lane, pB, pG, pS, pP);

  if (b < 32) {
    float2 xx[16];
#pragma unroll
    for (int i2 = 0; i2 < 16; i2++) xx[i2] = xT2[(size_t)i2 * NTOK + t];
    float o[4];
#pragma unroll
    for (int r = 0; r < 4; r++) {
      float aw = 0.f, ab = 0.f;
#pragma unroll
      for (int i2 = 0; i2 < 16; i2++) {
        float2 ww = w[r * 16 + i2];
        float2 W02 = ((const float2*)pW)[r * 16 + i2];   // broadcast ds_read
        aw += ww.x * xx[i2].x + ww.y * xx[i2].y;
        ab += W02.x * xx[i2].x + W02.y * xx[i2].y;
      }
      o[r] = ab + b0[4 * b + r] + aw * (1.0f / 128.0f);  // pre-relu, pre-bd0
    }
    h1T2[(size_t)(2 * b) * NTOK + t] = make_float2(o[0], o[1]);
    h1T2[(size_t)(2 * b + 1) * NTOK + t] = make_float2(o[2], o[3]);
  } else if (b == 32) {
#pragma unroll
    for (int m = 0; m < 64; m++)
      bd0T2[(size_t)m * NTOK + t] =
          make_float2(w[m].x * (1.0f / 128.0f), w[m].y * (1.0f / 128.0f));
  } else if (b == 33) {
#pragma unroll
    for (int m = 0; m < 64; m++)
      h2bT2[(size_t)m * NTOK + t] =
          make_float2(w[m].x * (1.0f / 128.0f), w[m].y * (1.0f / 128.0f));
  } else {
#pragma unroll
    for (int m = 0; m < 8; m++) {
      bd2v[(size_t)(2 * m) * NTOK + t] = w[m].x * (1.0f / 128.0f);
      bd2v[(size_t)(2 * m + 1) * NTOK + t] = w[m].y * (1.0f / 128.0f);
    }
  }
}

// K2: grid (8, 128), 256 thr. One wd1 row per block; h1 = relu(h1T2 + bd0T2) fused.
__global__ __launch_bounds__(256) void k2_layer1(
    const float2* __restrict__ zT2,
    const float* __restrict__ W1, const float* __restrict__ b1,
    const float* __restrict__ ffB, const float* __restrict__ ffG,
    const float* __restrict__ ffS, const int* __restrict__ ffP,
    const float2* __restrict__ h1T2, const float2* __restrict__ bd0T2,
    float* __restrict__ h2T) {
  __shared__ unsigned int ldsPerm[4 * 4096];
  __shared__ float pB[128], pG[128], pS[128], pW[128];
  __shared__ int pP[128];
  const int tid = threadIdx.x, lane = tid & 63, wsub = tid >> 6;
  const int jr = blockIdx.y;   // 0..127
  const int t = (blockIdx.x * 4 + wsub) * 64 + lane;

  stage_params(tid, ffB, ffG, ffS, ffP, 33 + jr, W1 + (size_t)jr * 128,
               pB, pG, pS, pP, pW);

  float2 w[64];
  load128T(w, zT2, t);
  ff_block(w, ldsPerm + wsub * 4096, lane, pB, pG, pS, pP);

  float aw = 0.f, ab = 0.f;
#pragma unroll
  for (int c2 = 0; c2 < 64; c2++) {
    float2 a = h1T2[(size_t)c2 * NTOK + t];    // coalesced
    float2 d = bd0T2[(size_t)c2 * NTOK + t];   // coalesced
    float e0 = fmaxf(a.x + d.x, 0.f), e1 = fmaxf(a.y + d.y, 0.f);
    float2 W12 = ((const float2*)pW)[c2];      // broadcast ds_read
    aw += w[c2].x * e0 + w[c2].y * e1;
    ab += W12.x * e0 + W12.y * e1;
  }
  h2T[(size_t)jr * NTOK + t] = ab + b1[jr] + aw * (1.0f / 128.0f);  // pre-relu
}

// K3: grid (8, 16), 256 thr. One wd2 row per block.
__global__ __launch_bounds__(256) void k3_layer2(
    const float2* __restrict__ zT2,
    const float* __restrict__ W2, const float* __restrict__ b2,
    const float* __restrict__ ffB, const float* __restrict__ ffG,
    const float* __restrict__ ffS, const int* __restrict__ ffP,
    const float* __restrict__ h2T, const float2* __restrict__ h2bT2,
    const float* __restrict__ bd2v, float* __restrict__ out) {
  __shared__ unsigned int ldsPerm[4 * 4096];
  __shared__ float pB[128], pG[128], pS[128], pW[128];
  __shared__ int pP[128];
  const int tid = threadIdx.x, lane = tid & 63, wsub = tid >> 6;
  const int b = blockIdx.y;   // 0..15
  const int t = (blockIdx.x * 4 + wsub) * 64 + lane;

  stage_params(tid, ffB, ffG, ffS, ffP, 162 + b, W2 + (size_t)b * 128,
               pB, pG, pS, pP, pW);

  float2 w[64];
  load128T(w, zT2, t);
  ff_block(w, ldsPerm + wsub * 4096, lane, pB, pG, pS, pP);

  float aw = 0.f, ab = 0.f;
#pragma unroll
  for (int c2 = 0; c2 < 64; c2++) {
    float p0 = h2T[(size_t)(2 * c2) * NTOK + t];       // coalesced
    float p1 = h2T[(size_t)(2 * c2 + 1) * NTOK + t];   // coalesced
    float2 q = h2bT2[(size_t)c2 * NTOK + t];           // coalesced
    float e0 = fmaxf(p0 + q.x, 0.f), e1 = fmaxf(p1 + q.y, 0.f);
    float2 W22 = ((const float2*)pW)[c2];              // broadcast ds_read
    aw += w[c2].x * e0 + w[c2].y * e1;
    ab += W22.x * e0 + W22.y * e1;
  }
  out[(size_t)t * YD + b] = ab + b2[b] + aw * (1.0f / 128.0f) + bd2v[(size_t)b * NTOK + t];
}

extern "C" void kernel_launch(void* const* d_in, const int* in_sizes, int n_in,
                              void* d_out, int out_size, void* d_ws, size_t ws_size,
                              hipStream_t stream) {
  const float* x  = (const float*)d_in[0];
  const float* z  = (const float*)d_in[1];
  const float* W0 = (const float*)d_in[2];
  const float* b0 = (const float*)d_in[3];
  const float* W1 = (const float*)d_in[4];
  const float* b1 = (const float*)d_in[5];
  const float* W2 = (const float*)d_in[6];
  const float* b2 = (const float*)d_in[7];
  const float* fB = (const float*)d_in[8];
  const float* fG = (const float*)d_in[9];
  const float* fS = (const float*)d_in[10];
  const int*   fP = (const int*)d_in[11];
  float* out = (float*)d_out;

  float2* zT2   = (float2*)d_ws;             // [64][2048] float2 = 1 MB
  float2* xT2   = zT2 + (size_t)64 * NTOK;   // [16][2048] float2 = 256 KB
  float2* h1T2  = xT2 + (size_t)16 * NTOK;   // [64][2048] float2 = 1 MB (pre-relu, no bd0)
  float2* bd0T2 = h1T2 + (size_t)64 * NTOK;  // 1 MB
  float2* h2bT2 = bd0T2 + (size_t)64 * NTOK; // 1 MB (bd1, /128 applied)
  float*  h2T   = (float*)(h2bT2 + (size_t)64 * NTOK);  // [128][2048] f32 = 1 MB
  float*  bd2v  = h2T + (size_t)HD * NTOK;   // [16][2048] = 128 KB

  k0_transpose<<<dim3(32), 64, 0, stream>>>(z, x, zT2, xT2);
  k1_layer0<<<dim3(8, 35), 256, 0, stream>>>(xT2, zT2, W0, b0, fB, fG, fS, fP,
                                             h1T2, bd0T2, h2bT2, bd2v);
  k2_layer1<<<dim3(8, 128), 256, 0, stream>>>(zT2, W1, b1, fB, fG, fS, fP,
                                              h1T2, bd0T2, h2T);
  k3_layer2<<<dim3(8, 16), 256, 0, stream>>>(zT2, W2, b2, fB, fG, fS, fP,
                                             h2T, h2bT2, bd2v, out);
}